// Round 1
// baseline (533.174 us; speedup 1.0000x reference)
//
#include <hip/hip_runtime.h>
#include <hip/hip_bf16.h>

typedef __bf16 bf16_t;
typedef bf16_t bf16x8 __attribute__((ext_vector_type(8)));
typedef float  f32x4  __attribute__((ext_vector_type(4)));

#define BM 128
#define BN 128
#define BK 32
#define M_TOK 2048
#define N_OUT 11008
#define K_IN  4096

__global__ __launch_bounds__(256)
void qlinear_gemm(const float* __restrict__ X,
                  const int*   __restrict__ Q,
                  const float* __restrict__ S,
                  const float* __restrict__ Z,
                  const float* __restrict__ Bias,
                  float* __restrict__ O)
{
    __shared__ bf16_t As[BM][BK];
    __shared__ bf16_t Bs[BN][BK];

    const int tid  = threadIdx.x;
    const int lane = tid & 63;
    const int wid  = tid >> 6;
    const int wr   = wid >> 1;   // wave row 0..1
    const int wc   = wid & 1;    // wave col 0..1
    const int fr   = lane & 15;  // fragment row/col within 16
    const int fg   = lane >> 4;  // k-group 0..3

    const int bm = blockIdx.y * BM;
    const int bn = blockIdx.x * BN;

    // staging: each of 256 threads stages 16 elems of A and 16 of B per K-step
    const int srow = tid >> 1;          // 0..127
    const int scol = (tid & 1) << 4;    // 0 or 16

    const float s_n  = S[bn + srow];
    const float zs_n = Z[bn + srow] * s_n;

    const float* xptr = X + (size_t)(bm + srow) * K_IN + scol;
    const int*   qptr = Q + (size_t)(bn + srow) * K_IN + scol;

    f32x4 acc[4][4] = {};

    for (int k0 = 0; k0 < K_IN; k0 += BK) {
        // ---- load A slice (f32) ----
        float a[16];
        {
            const float4* s4 = (const float4*)(xptr + k0);
            *(float4*)(a +  0) = s4[0];
            *(float4*)(a +  4) = s4[1];
            *(float4*)(a +  8) = s4[2];
            *(float4*)(a + 12) = s4[3];
        }
        // ---- load B slice (int32 quantized), dequant in f32 ----
        int qi[16];
        {
            const int4* s4 = (const int4*)(qptr + k0);
            *(int4*)(qi +  0) = s4[0];
            *(int4*)(qi +  4) = s4[1];
            *(int4*)(qi +  8) = s4[2];
            *(int4*)(qi + 12) = s4[3];
        }
        float b[16];
        #pragma unroll
        for (int j = 0; j < 16; ++j)
            b[j] = (float)qi[j] * s_n - zs_n;

        // ---- convert to bf16 and write LDS (2x 16B per operand) ----
        bf16x8 pa0, pa1, pb0, pb1;
        #pragma unroll
        for (int j = 0; j < 8; ++j) {
            pa0[j] = (bf16_t)a[j];
            pa1[j] = (bf16_t)a[j + 8];
            pb0[j] = (bf16_t)b[j];
            pb1[j] = (bf16_t)b[j + 8];
        }
        *(bf16x8*)&As[srow][scol]     = pa0;
        *(bf16x8*)&As[srow][scol + 8] = pa1;
        *(bf16x8*)&Bs[srow][scol]     = pb0;
        *(bf16x8*)&Bs[srow][scol + 8] = pb1;

        __syncthreads();

        // ---- fragments + MFMA ----
        bf16x8 af[4], bfv[4];
        #pragma unroll
        for (int m = 0; m < 4; ++m)
            af[m] = *(const bf16x8*)&As[wr * 64 + m * 16 + fr][fg * 8];
        #pragma unroll
        for (int n = 0; n < 4; ++n)
            bfv[n] = *(const bf16x8*)&Bs[wc * 64 + n * 16 + fr][fg * 8];

        #pragma unroll
        for (int m = 0; m < 4; ++m)
            #pragma unroll
            for (int n = 0; n < 4; ++n)
                acc[m][n] = __builtin_amdgcn_mfma_f32_16x16x32_bf16(
                    af[m], bfv[n], acc[m][n], 0, 0, 0);

        __syncthreads();
    }

    // ---- epilogue: add bias, store f32 ----
    // C/D mapping (m89/m91): col = lane&15, row = (lane>>4)*4 + reg
    #pragma unroll
    for (int n = 0; n < 4; ++n) {
        const int col  = bn + wc * 64 + n * 16 + fr;
        const float bv = Bias[col];
        #pragma unroll
        for (int m = 0; m < 4; ++m) {
            const int row0 = bm + wr * 64 + m * 16 + fg * 4;
            #pragma unroll
            for (int r = 0; r < 4; ++r) {
                O[(size_t)(row0 + r) * N_OUT + col] = acc[m][n][r] + bv;
            }
        }
    }
}

extern "C" void kernel_launch(void* const* d_in, const int* in_sizes, int n_in,
                              void* d_out, int out_size, void* d_ws, size_t ws_size,
                              hipStream_t stream) {
    const float* X    = (const float*)d_in[0];
    const int*   Q    = (const int*)d_in[1];
    const float* S    = (const float*)d_in[2];
    const float* Z    = (const float*)d_in[3];
    const float* Bias = (const float*)d_in[4];
    float* O = (float*)d_out;

    dim3 grid(N_OUT / BN, M_TOK / BM);  // 86 x 16 = 1376 blocks
    qlinear_gemm<<<grid, 256, 0, stream>>>(X, Q, S, Z, Bias, O);
}

// Round 2
// 317.029 us; speedup vs baseline: 1.6818x; 1.6818x over previous
//
#include <hip/hip_runtime.h>
#include <hip/hip_bf16.h>
#include <stdint.h>

typedef __bf16 bf16_t;
typedef bf16_t bf16x8 __attribute__((ext_vector_type(8)));
typedef float  f32x4  __attribute__((ext_vector_type(4)));

#define BM 128
#define BN 128
#define BK 32
#define M_TOK 2048
#define N_OUT 11008
#define K_IN  4096

#define GLDS16(gptr, lptr)                                                     \
    __builtin_amdgcn_global_load_lds(                                          \
        (__attribute__((address_space(1))) void*)(gptr),                       \
        (__attribute__((address_space(3))) void*)(lptr), 16, 0, 0)

// ---------------- pre-pass 1: dequant W int32 -> bf16 ----------------
__global__ __launch_bounds__(256)
void dequant_w(const int* __restrict__ Q, const float* __restrict__ S,
               const float* __restrict__ Z, bf16_t* __restrict__ W)
{
    const size_t total8 = (size_t)N_OUT * K_IN / 8;
    const size_t stride = (size_t)gridDim.x * blockDim.x;
    for (size_t i = (size_t)blockIdx.x * blockDim.x + threadIdx.x; i < total8; i += stride) {
        const size_t e0 = i * 8;
        const int row = (int)(e0 >> 12);  // /4096, 8 | 4096 so row uniform per chunk
        const float s  = S[row];
        const float zs = Z[row] * s;
        const int4* q4 = (const int4*)(Q + e0);
        const int4 qa = q4[0], qb = q4[1];
        bf16x8 w;
        w[0] = (bf16_t)((float)qa.x * s - zs);
        w[1] = (bf16_t)((float)qa.y * s - zs);
        w[2] = (bf16_t)((float)qa.z * s - zs);
        w[3] = (bf16_t)((float)qa.w * s - zs);
        w[4] = (bf16_t)((float)qb.x * s - zs);
        w[5] = (bf16_t)((float)qb.y * s - zs);
        w[6] = (bf16_t)((float)qb.z * s - zs);
        w[7] = (bf16_t)((float)qb.w * s - zs);
        *(bf16x8*)(W + e0) = w;
    }
}

// ---------------- pre-pass 2: X f32 -> bf16 ----------------
__global__ __launch_bounds__(256)
void cvt_x(const float* __restrict__ X, bf16_t* __restrict__ Xb)
{
    const size_t total8 = (size_t)M_TOK * K_IN / 8;
    const size_t stride = (size_t)gridDim.x * blockDim.x;
    for (size_t i = (size_t)blockIdx.x * blockDim.x + threadIdx.x; i < total8; i += stride) {
        const size_t e0 = i * 8;
        const float4* x4 = (const float4*)(X + e0);
        const float4 xa = x4[0], xb = x4[1];
        bf16x8 v;
        v[0] = (bf16_t)xa.x; v[1] = (bf16_t)xa.y;
        v[2] = (bf16_t)xa.z; v[3] = (bf16_t)xa.w;
        v[4] = (bf16_t)xb.x; v[5] = (bf16_t)xb.y;
        v[6] = (bf16_t)xb.z; v[7] = (bf16_t)xb.w;
        *(bf16x8*)(Xb + e0) = v;
    }
}

// ---------------- main GEMM: m97-structure bf16, global_load_lds ----------------
__global__ __launch_bounds__(256)
void gemm_bf16(const bf16_t* __restrict__ A,   // [M_TOK][K_IN]
               const bf16_t* __restrict__ B,   // [N_OUT][K_IN]  (B^T layout)
               const float* __restrict__ Bias,
               float* __restrict__ O)
{
    __shared__ bf16_t As[BM][BK];   // 8 KB
    __shared__ bf16_t Bs[BN][BK];   // 8 KB

    const int tid  = threadIdx.x;
    const int lane = tid & 63;
    const int wid  = tid >> 6;
    const int wr   = wid >> 1;
    const int wc   = wid & 1;
    const int fr   = lane & 15;
    const int fg   = lane >> 4;

    const int bm = blockIdx.y * BM;
    const int bn = blockIdx.x * BN;

    // staging source: thread tid covers LDS linear chunk tid*16B
    // row = tid>>2 (of 64), col elems = (tid&3)*8
    const bf16_t* ga = A + (size_t)(bm + (tid >> 2)) * K_IN + ((tid & 3) << 3);
    const bf16_t* gb = B + (size_t)(bn + (tid >> 2)) * K_IN + ((tid & 3) << 3);
    char* lA = (char*)&As[0][0] + (wid << 10);   // wave-uniform base
    char* lB = (char*)&Bs[0][0] + (wid << 10);

    f32x4 acc[4][4] = {};

    for (int k0 = 0; k0 < K_IN; k0 += BK) {
        GLDS16(ga + k0,                lA);
        GLDS16(ga + k0 + 64 * K_IN,    lA + 4096);
        GLDS16(gb + k0,                lB);
        GLDS16(gb + k0 + 64 * K_IN,    lB + 4096);
        __syncthreads();   // drains vmcnt before barrier (compiler-emitted)

        bf16x8 af[4], bfv[4];
        #pragma unroll
        for (int m = 0; m < 4; ++m)
            af[m] = *(const bf16x8*)&As[wr * 64 + m * 16 + fr][fg * 8];
        #pragma unroll
        for (int n = 0; n < 4; ++n)
            bfv[n] = *(const bf16x8*)&Bs[wc * 64 + n * 16 + fr][fg * 8];

        #pragma unroll
        for (int m = 0; m < 4; ++m)
            #pragma unroll
            for (int n = 0; n < 4; ++n)
                acc[m][n] = __builtin_amdgcn_mfma_f32_16x16x32_bf16(
                    af[m], bfv[n], acc[m][n], 0, 0, 0);

        __syncthreads();
    }

    // epilogue: C/D mapping col=lane&15, row=(lane>>4)*4+reg
    #pragma unroll
    for (int n = 0; n < 4; ++n) {
        const int col  = bn + wc * 64 + n * 16 + fr;
        const float bv = Bias[col];
        #pragma unroll
        for (int m = 0; m < 4; ++m) {
            const int row0 = bm + wr * 64 + m * 16 + fg * 4;
            #pragma unroll
            for (int r = 0; r < 4; ++r)
                O[(size_t)(row0 + r) * N_OUT + col] = acc[m][n][r] + bv;
        }
    }
}

// ---------------- fallback (round-1 fused kernel) if ws too small ----------------
__global__ __launch_bounds__(256)
void qlinear_fused(const float* __restrict__ X,
                   const int*   __restrict__ Q,
                   const float* __restrict__ S,
                   const float* __restrict__ Z,
                   const float* __restrict__ Bias,
                   float* __restrict__ O)
{
    __shared__ bf16_t As[BM][BK];
    __shared__ bf16_t Bs[BN][BK];
    const int tid = threadIdx.x, lane = tid & 63, wid = tid >> 6;
    const int wr = wid >> 1, wc = wid & 1, fr = lane & 15, fg = lane >> 4;
    const int bm = blockIdx.y * BM, bn = blockIdx.x * BN;
    const int srow = tid >> 1, scol = (tid & 1) << 4;
    const float s_n = S[bn + srow];
    const float zs_n = Z[bn + srow] * s_n;
    const float* xptr = X + (size_t)(bm + srow) * K_IN + scol;
    const int*   qptr = Q + (size_t)(bn + srow) * K_IN + scol;
    f32x4 acc[4][4] = {};
    for (int k0 = 0; k0 < K_IN; k0 += BK) {
        float a[16]; int qi[16];
        { const float4* s4 = (const float4*)(xptr + k0);
          *(float4*)(a+0)=s4[0]; *(float4*)(a+4)=s4[1]; *(float4*)(a+8)=s4[2]; *(float4*)(a+12)=s4[3]; }
        { const int4* s4 = (const int4*)(qptr + k0);
          *(int4*)(qi+0)=s4[0]; *(int4*)(qi+4)=s4[1]; *(int4*)(qi+8)=s4[2]; *(int4*)(qi+12)=s4[3]; }
        float b[16];
        #pragma unroll
        for (int j = 0; j < 16; ++j) b[j] = (float)qi[j] * s_n - zs_n;
        bf16x8 pa0, pa1, pb0, pb1;
        #pragma unroll
        for (int j = 0; j < 8; ++j) {
            pa0[j]=(bf16_t)a[j]; pa1[j]=(bf16_t)a[j+8];
            pb0[j]=(bf16_t)b[j]; pb1[j]=(bf16_t)b[j+8];
        }
        *(bf16x8*)&As[srow][scol]   = pa0; *(bf16x8*)&As[srow][scol+8] = pa1;
        *(bf16x8*)&Bs[srow][scol]   = pb0; *(bf16x8*)&Bs[srow][scol+8] = pb1;
        __syncthreads();
        bf16x8 af[4], bfv[4];
        #pragma unroll
        for (int m = 0; m < 4; ++m) af[m] = *(const bf16x8*)&As[wr*64+m*16+fr][fg*8];
        #pragma unroll
        for (int n = 0; n < 4; ++n) bfv[n] = *(const bf16x8*)&Bs[wc*64+n*16+fr][fg*8];
        #pragma unroll
        for (int m = 0; m < 4; ++m)
            #pragma unroll
            for (int n = 0; n < 4; ++n)
                acc[m][n] = __builtin_amdgcn_mfma_f32_16x16x32_bf16(af[m], bfv[n], acc[m][n], 0,0,0);
        __syncthreads();
    }
    #pragma unroll
    for (int n = 0; n < 4; ++n) {
        const int col = bn + wc*64 + n*16 + fr;
        const float bv = Bias[col];
        #pragma unroll
        for (int m = 0; m < 4; ++m) {
            const int row0 = bm + wr*64 + m*16 + fg*4;
            #pragma unroll
            for (int r = 0; r < 4; ++r)
                O[(size_t)(row0 + r) * N_OUT + col] = acc[m][n][r] + bv;
        }
    }
}

extern "C" void kernel_launch(void* const* d_in, const int* in_sizes, int n_in,
                              void* d_out, int out_size, void* d_ws, size_t ws_size,
                              hipStream_t stream) {
    const float* X    = (const float*)d_in[0];
    const int*   Q    = (const int*)d_in[1];
    const float* S    = (const float*)d_in[2];
    const float* Z    = (const float*)d_in[3];
    const float* Bias = (const float*)d_in[4];
    float* O = (float*)d_out;

    const size_t wbytes = (size_t)N_OUT * K_IN * sizeof(bf16_t);  // 90,177,536
    const size_t xbytes = (size_t)M_TOK * K_IN * sizeof(bf16_t);  // 16,777,216

    if (ws_size >= wbytes + xbytes) {
        bf16_t* W  = (bf16_t*)d_ws;
        bf16_t* Xb = (bf16_t*)((char*)d_ws + wbytes);
        dequant_w<<<2048, 256, 0, stream>>>(Q, S, Z, W);
        cvt_x<<<1024, 256, 0, stream>>>(X, Xb);
        dim3 grid(N_OUT / BN, M_TOK / BM);  // 86 x 16
        gemm_bf16<<<grid, 256, 0, stream>>>(Xb, W, Bias, O);
    } else {
        dim3 grid(N_OUT / BN, M_TOK / BM);
        qlinear_fused<<<grid, 256, 0, stream>>>(X, Q, S, Z, Bias, O);
    }
}